// Round 1
// baseline (17496.983 us; speedup 1.0000x reference)
//
#include <hip/hip_runtime.h>
#include <math.h>

// Problem constants (from reference)
#define B_      4
#define F_BINS  128
#define T_FULL  16384
#define J_T     4
#define NW      8          // wavelets per octave
#define CH      16         // 8 real + 8 imag conv channels
#define KF      33
#define KT      129
#define KSZ     (KF * KT)  // 4257

// Tiling
#define FT      16                 // output F tile
#define TT      64                 // output T tile
#define TCOLS   (TT + KT - 1)      // 192 input cols needed
#define PITCH   196                // padded LDS row pitch (floats)
#define FROWS   (FT + KF - 1)      // 48 input rows needed

// ---------------------------------------------------------------------------
// Kernel 1: build T-pooled pyramid L1 (T/2), L2 (T/4), L3 (T/8) from x.
// Pool-by-2 chaining == direct mean over 2/4/8 (all linear means).
// ---------------------------------------------------------------------------
__global__ __launch_bounds__(256) void pool_pyramid(
    const float* __restrict__ x,
    float* __restrict__ L1, float* __restrict__ L2, float* __restrict__ L3) {
  int idx = blockIdx.x * 256 + threadIdx.x;      // over B_*F_BINS*2048
  int row = idx >> 11;                           // b*128+f  (512 rows)
  int g   = idx & 2047;                          // group of 8 input samples
  const float4* p = (const float4*)(x + (size_t)row * T_FULL + (size_t)g * 8);
  float4 a = p[0], b = p[1];
  float s0 = (a.x + a.y) * 0.5f, s1 = (a.z + a.w) * 0.5f;
  float s2 = (b.x + b.y) * 0.5f, s3 = (b.z + b.w) * 0.5f;
  *(float4*)(L1 + (size_t)row * 8192 + (size_t)g * 4) = make_float4(s0, s1, s2, s3);
  float q0 = (s0 + s1) * 0.5f, q1 = (s2 + s3) * 0.5f;
  *(float2*)(L2 + (size_t)row * 4096 + (size_t)g * 2) = make_float2(q0, q1);
  L3[(size_t)row * 2048 + g] = (q0 + q1) * 0.5f;
}

// ---------------------------------------------------------------------------
// Kernel 2: one octave: SAME conv (33x129, 16 ch) + modulus + avg-pool(T,w).
// Block = 256 threads -> 16(F) x 64(T) output pixels, 4 T-pixels/thread.
// ---------------------------------------------------------------------------
__global__ __launch_bounds__(256) void conv_oct(
    const float* __restrict__ xin,        // (B, 128, Tj)
    const float* __restrict__ wav_real,   // (4, 8, 33, 129)
    const float* __restrict__ wav_imag,
    float* __restrict__ out,              // (B, 32, 128, 1024)
    int Tj, int w, int oct) {
  __shared__ __align__(16) float sm[FROWS * PITCH];   // 48*196*4 = 37632 B

  const int tid = threadIdx.x;
  const int t0  = blockIdx.x * TT;
  const int f0  = blockIdx.y * FT;
  const int b   = blockIdx.z;

  // ---- stage input tile (zero-padded SAME borders) into LDS ----
  const float* xb = xin + (size_t)b * F_BINS * (size_t)Tj;
  for (int i = tid; i < FROWS * TCOLS; i += 256) {
    int fl = i / TCOLS;
    int tl = i - fl * TCOLS;
    int gf = f0 - (KF / 2) + fl;
    int gt = t0 - (KT / 2) + tl;
    float v = 0.0f;
    if ((unsigned)gf < (unsigned)F_BINS && (unsigned)gt < (unsigned)Tj)
      v = xb[(size_t)gf * Tj + gt];
    sm[fl * PITCH + tl] = v;
  }
  __syncthreads();

  const int f_local = tid >> 4;            // 0..15
  const int t_base  = (tid & 15) << 2;     // 0,4,...,60

  const float* wr0 = wav_real + (size_t)oct * NW * KSZ;
  const float* wi0 = wav_imag + (size_t)oct * NW * KSZ;

  float acc[CH][4];
#pragma unroll
  for (int c = 0; c < CH; ++c)
#pragma unroll
    for (int k = 0; k < 4; ++k) acc[c][k] = 0.0f;

#pragma unroll 1
  for (int df = 0; df < KF; ++df) {
    const float* xr  = &sm[(f_local + df) * PITCH + t_base];
    const float* wrd = wr0 + df * KT;
    const float* wid = wi0 + df * KT;

    float4 a = *(const float4*)&xr[0];      // aligned: t_base%4==0, PITCH%4==0
#pragma unroll 1
    for (int dt4 = 0; dt4 < KT - 1; dt4 += 4) {
      float4 bb = *(const float4*)&xr[dt4 + 4];
      float vv[7] = {a.x, a.y, a.z, a.w, bb.x, bb.y, bb.z};
#pragma unroll
      for (int c = 0; c < CH; ++c) {
        const float* wp = (c < NW) ? (wrd + (size_t)c * KSZ)
                                   : (wid + (size_t)(c - NW) * KSZ);
#pragma unroll
        for (int d = 0; d < 4; ++d) {
          float wvv = wp[dt4 + d];          // wave-uniform -> scalar load
#pragma unroll
          for (int k = 0; k < 4; ++k)
            acc[c][k] = fmaf(vv[d + k], wvv, acc[c][k]);
        }
      }
      a = bb;
    }
    // remainder tap dt = KT-1 = 128; 'a' now holds xr[128..131]
    {
      float vv2[4] = {a.x, a.y, a.z, a.w};
#pragma unroll
      for (int c = 0; c < CH; ++c) {
        float wvv = (c < NW) ? wrd[(size_t)c * KSZ + (KT - 1)]
                             : wid[(size_t)(c - NW) * KSZ + (KT - 1)];
#pragma unroll
        for (int k = 0; k < 4; ++k)
          acc[c][k] = fmaf(vv2[k], wvv, acc[c][k]);
      }
    }
  }

  // ---- modulus into LDS (reuse sm), then average-pool along T ----
  __syncthreads();
#pragma unroll
  for (int c = 0; c < NW; ++c)
#pragma unroll
    for (int k = 0; k < 4; ++k) {
      float re = acc[c][k], im = acc[c + NW][k];
      sm[(f_local * NW + c) * TT + t_base + k] = sqrtf(re * re + im * im);
    }
  __syncthreads();

  const int npo = TT / w;                    // pooled outputs per f row
  const float inv = 1.0f / (float)w;
  const int total = FT * NW * npo;
  for (int o = tid; o < total; o += 256) {
    int tp   = o % npo;
    int rest = o / npo;
    int c    = rest % NW;
    int fl   = rest / NW;
    float s = 0.0f;
    for (int q = 0; q < w; ++q) s += sm[(fl * NW + c) * TT + tp * w + q];
    size_t oi = (((size_t)b * 32 + (size_t)oct * NW + c) * F_BINS + (f0 + fl)) * 1024
              + (size_t)(t0 / w) + tp;
    out[oi] = s * inv;
  }
}

// ---------------------------------------------------------------------------
extern "C" void kernel_launch(void* const* d_in, const int* in_sizes, int n_in,
                              void* d_out, int out_size, void* d_ws, size_t ws_size,
                              hipStream_t stream) {
  const float* x  = (const float*)d_in[0];
  const float* wr = (const float*)d_in[1];
  const float* wi = (const float*)d_in[2];
  float* out = (float*)d_out;

  float* L1 = (float*)d_ws;                       // (4,128,8192)
  float* L2 = L1 + (size_t)B_ * F_BINS * 8192;    // (4,128,4096)
  float* L3 = L2 + (size_t)B_ * F_BINS * 4096;    // (4,128,2048)

  pool_pyramid<<<(B_ * F_BINS * 2048) / 256, 256, 0, stream>>>(x, L1, L2, L3);

  conv_oct<<<dim3(T_FULL / TT, F_BINS / FT, B_), 256, 0, stream>>>(
      x,  wr, wi, out, T_FULL, 16, 0);
  conv_oct<<<dim3(8192 / TT, F_BINS / FT, B_), 256, 0, stream>>>(
      L1, wr, wi, out, 8192, 8, 1);
  conv_oct<<<dim3(4096 / TT, F_BINS / FT, B_), 256, 0, stream>>>(
      L2, wr, wi, out, 4096, 4, 2);
  conv_oct<<<dim3(2048 / TT, F_BINS / FT, B_), 256, 0, stream>>>(
      L3, wr, wi, out, 2048, 2, 3);
}

// Round 2
// 2775.337 us; speedup vs baseline: 6.3045x; 6.3045x over previous
//
#include <hip/hip_runtime.h>
#include <math.h>

#define B_      4
#define F_BINS  128
#define T_FULL  16384
#define NW      8
#define KF      33
#define KT      129

typedef __attribute__((ext_vector_type(8))) short short8;
typedef __attribute__((ext_vector_type(4))) float f32x4;

union ABFrag { uint u[4]; short8 v; };

__device__ __forceinline__ ushort f2bf(float v) {
  unsigned u = __float_as_uint(v);
  unsigned r = (u + 0x7FFFu + ((u >> 16) & 1u)) >> 16;
  return (ushort)r;
}

// ---------------------------------------------------------------------------
// prep_w: build shifted/padded bf16 weights
//   wq[oct 4][par 2][ch 16][dt 132][d 48], par0: df=d-8, par1: df=d-7
//   (zero outside df in [0,32], dt in [0,128])
// ---------------------------------------------------------------------------
__global__ __launch_bounds__(256) void prep_w(
    const float* __restrict__ wr, const float* __restrict__ wi,
    ushort* __restrict__ wq) {
  int idx = blockIdx.x * 256 + threadIdx.x;      // 4*2*16*132*48 = 811008
  int d   = idx % 48;
  int t   = (idx / 48) % 132;
  int ch  = (idx / (48 * 132)) % 16;
  int par = (idx / (48 * 132 * 16)) % 2;
  int oct = idx / (48 * 132 * 16 * 2);
  int df  = d - 8 + par;
  float v = 0.f;
  if (df >= 0 && df < KF && t < KT) {
    const float* src = (ch < 8) ? wr : wi;
    v = src[(((size_t)oct * 8 + (ch & 7)) * KF + df) * KT + t];
  }
  wq[idx] = f2bf(v);
}

// ---------------------------------------------------------------------------
// prep_x: bf16 transposed pyramid  xTj[b][T_j][128f]  for j=0..3
// ---------------------------------------------------------------------------
__global__ __launch_bounds__(256) void prep_x(
    const float* __restrict__ x,
    ushort* __restrict__ xT0, ushort* __restrict__ xT1,
    ushort* __restrict__ xT2, ushort* __restrict__ xT3) {
  __shared__ float lt[128 * 65];
  const int b  = blockIdx.y;
  const int t0 = blockIdx.x * 64;
  const int tid = threadIdx.x;
  const int wv = tid >> 6, lane = tid & 63;
#pragma unroll
  for (int rep = 0; rep < 32; ++rep) {
    int f = rep * 4 + wv;
    lt[f * 65 + lane] = x[((size_t)b * 128 + f) * T_FULL + t0 + lane];
  }
  __syncthreads();
  ushort* dst[4] = {xT0, xT1, xT2, xT3};
  const int Ts[4] = {16384, 8192, 4096, 2048};
  for (int lvl = 0; lvl < 4; ++lvl) {
    int nt = 64 >> lvl, w = 1 << lvl;
    float inv = 1.f / (float)w;
    int tasks = nt * 16;
    for (int i = tid; i < tasks; i += 256) {
      int tl = i >> 4, fc = i & 15;
      __align__(16) ushort vs[8];
#pragma unroll
      for (int e = 0; e < 8; ++e) {
        float a = 0.f;
        for (int m = 0; m < w; ++m) a += lt[(fc * 8 + e) * 65 + tl * w + m];
        vs[e] = f2bf(a * inv);
      }
      ushort* pdst = dst[lvl] + ((size_t)b * Ts[lvl] + (t0 >> lvl) + tl) * 128 + fc * 8;
      *(uint4*)pdst = *(const uint4*)vs;
    }
  }
}

// ---------------------------------------------------------------------------
// conv_mfma: one octave. Block = 256 thr = 4 waves; tile = 16 f_out x 256 t.
// MFMA 16x16x32_bf16: M=ch16 (A=weights), N=pos16 (B=x), K=(8 df x 4 dt).
// x staged transposed in LDS (pitch 56); weights read from global (L2).
// ---------------------------------------------------------------------------
template<int WP, int OCT>
__global__ __launch_bounds__(256) void conv_mfma(
    const ushort* __restrict__ xT, const ushort* __restrict__ wq,
    float* __restrict__ out, int Tj) {
  __shared__ ushort xt[388 * 56];
  const int tid = threadIdx.x;
  const int t0 = blockIdx.x * 256;
  const int f0 = blockIdx.y * 16;
  const int b  = blockIdx.z;

  // ---- stage transposed x tile: rows tloc 0..387 (t = t0-64+row), cols f0-16+[0,48) ----
  for (int i = tid; i < 388 * 6; i += 256) {
    int row = i / 6, fc = i % 6;
    int t = t0 - 64 + row;
    int f = f0 - 16 + fc * 8;             // chunk fully in or fully out of range
    uint4 v = make_uint4(0u, 0u, 0u, 0u);
    if (t >= 0 && t < Tj && f >= 0 && f < 128)
      v = *(const uint4*)(xT + ((size_t)b * Tj + t) * 128 + f);
    *(uint4*)&xt[row * 56 + fc * 8] = v;
  }
  __syncthreads();

  const int wave = tid >> 6, lane = tid & 63;
  const int p = lane & 15;                 // A-row = channel, B-col = position
  const int g = lane >> 4;                 // k-group

  for (int fp = 0; fp < 8; ++fp) {
    const int par = fp & 1;
    const ushort* wbase = wq + (((size_t)OCT * 2 + par) * 16 + p) * (132 * 48);
    const int dstart0 = par ? (7 - fp) : (8 - fp);   // even in both cases
    f32x4 acc[2][4];
#pragma unroll
    for (int a = 0; a < 2; ++a)
#pragma unroll
      for (int r = 0; r < 4; ++r) { f32x4 z = {0.f, 0.f, 0.f, 0.f}; acc[a][r] = z; }

    for (int c = 0; c < 33; ++c) {
      const int d0 = 4 * c;
      const int uoff_c = (p + g + d0) * 56 + wave * 3584;
      const ushort* wrow = wbase + (d0 + g) * 48 + dstart0;
      short8 Aprev, Acur;
#pragma unroll
      for (int s = 0; s <= 5; ++s) {
        if (s < 5) {
          const uint* ap = (const uint*)(wrow + 8 * s);
          ABFrag fa;
          fa.u[0] = ap[0]; fa.u[1] = ap[1]; fa.u[2] = ap[2]; fa.u[3] = ap[3];
          Acur = fa.v;
        }
#pragma unroll
        for (int fr = 0; fr < 4; ++fr) {
          short8 bv = *(const short8*)&xt[uoff_c + fr * 896 + s * 8];
          if (s < 5)
            acc[0][fr] = __builtin_amdgcn_mfma_f32_16x16x32_bf16(Acur, bv, acc[0][fr], 0, 0, 0);
          if (s > 0)
            acc[1][fr] = __builtin_amdgcn_mfma_f32_16x16x32_bf16(Aprev, bv, acc[1][fr], 0, 0, 0);
        }
        Aprev = Acur;
      }
    }

    // ---- epilogue: modulus (lane^32 pairs re/im) + avg-pool via butterfly ----
    const float invw = 1.f / (float)WP;
#pragma unroll
    for (int f2 = 0; f2 < 2; ++f2) {
      const int fo = f0 + fp + 8 * f2;
#pragma unroll
      for (int fr = 0; fr < 4; ++fr) {
        const int tbase = t0 + 16 * (4 * wave + fr);
#pragma unroll
        for (int r = 0; r < 4; ++r) {
          float a = acc[f2][fr][r];
          float o = __shfl_xor(a, 32);
          float m = sqrtf(a * a + o * o);
#pragma unroll
          for (int mask = WP / 2; mask >= 1; mask >>= 1)
            m += __shfl_xor(m, mask);
          if (((p & (WP - 1)) == 0) && g < 2) {
            int ch = 4 * g + r;
            int tcol = (tbase + p) / WP;
            out[(((size_t)b * 32 + OCT * 8 + ch) * 128 + fo) * 1024 + tcol] = m * invw;
          }
        }
      }
    }
  }
}

// ---------------------------------------------------------------------------
extern "C" void kernel_launch(void* const* d_in, const int* in_sizes, int n_in,
                              void* d_out, int out_size, void* d_ws, size_t ws_size,
                              hipStream_t stream) {
  const float* x  = (const float*)d_in[0];
  const float* wr = (const float*)d_in[1];
  const float* wi = (const float*)d_in[2];
  float* out = (float*)d_out;

  ushort* xT0 = (ushort*)d_ws;                       // 4*16384*128
  ushort* xT1 = xT0 + (size_t)4 * 16384 * 128;       // 4*8192*128
  ushort* xT2 = xT1 + (size_t)4 * 8192 * 128;        // 4*4096*128
  ushort* xT3 = xT2 + (size_t)4 * 4096 * 128;        // 4*2048*128
  ushort* wq  = xT3 + (size_t)4 * 2048 * 128;        // 811008

  prep_w<<<811008 / 256, 256, 0, stream>>>(wr, wi, wq);
  prep_x<<<dim3(T_FULL / 64, B_), 256, 0, stream>>>(x, xT0, xT1, xT2, xT3);

  conv_mfma<16, 0><<<dim3(64, 8, 4), 256, 0, stream>>>(xT0, wq, out, 16384);
  conv_mfma< 8, 1><<<dim3(32, 8, 4), 256, 0, stream>>>(xT1, wq, out, 8192);
  conv_mfma< 4, 2><<<dim3(16, 8, 4), 256, 0, stream>>>(xT2, wq, out, 4096);
  conv_mfma< 2, 3><<<dim3( 8, 8, 4), 256, 0, stream>>>(xT3, wq, out, 2048);
}

// Round 3
// 2074.066 us; speedup vs baseline: 8.4361x; 1.3381x over previous
//
#include <hip/hip_runtime.h>
#include <math.h>

#define B_      4
#define F_BINS  128
#define T_FULL  16384
#define NW      8
#define KF      33
#define KT      129

typedef __attribute__((ext_vector_type(8))) short short8;
typedef __attribute__((ext_vector_type(4))) float f32x4;
typedef uint uint4a __attribute__((ext_vector_type(4), aligned(4)));

union ABFrag { uint4a u; short8 v; };

__device__ __forceinline__ ushort f2bf(float v) {
  unsigned u = __float_as_uint(v);
  unsigned r = (u + 0x7FFFu + ((u >> 16) & 1u)) >> 16;
  return (ushort)r;
}

__device__ __forceinline__ short8 load_a16(const ushort* p) {
  ABFrag f; f.u = *(const uint4a*)p; return f.v;
}

// ---------------------------------------------------------------------------
// prep_w: fp-shifted, zero-padded bf16 weights
//   wq[oct 4][fp 8][ch 16][dt 132][d2 40] = wav[ch][df = d2 - fp][dt]
//   (zero outside df in [0,33), dt in [0,129))
//   Row stride 40*2B = 80 B -> every 16B A-fragment load is 16B-aligned.
// ---------------------------------------------------------------------------
__global__ __launch_bounds__(256) void prep_w(
    const float* __restrict__ wr, const float* __restrict__ wi,
    ushort* __restrict__ wq) {
  int idx = blockIdx.x * 256 + threadIdx.x;      // 4*8*16*132*40 = 2703360
  int d2  = idx % 40;
  int dt  = (idx / 40) % 132;
  int ch  = (idx / (40 * 132)) % 16;
  int fp  = (idx / (40 * 132 * 16)) % 8;
  int oct = idx / (40 * 132 * 16 * 8);
  int df  = d2 - fp;
  float v = 0.f;
  if (df >= 0 && df < KF && dt < KT) {
    const float* src = (ch < 8) ? wr : wi;
    v = src[(((size_t)oct * 8 + (ch & 7)) * KF + df) * KT + dt];
  }
  wq[idx] = f2bf(v);
}

// ---------------------------------------------------------------------------
// prep_x: bf16 transposed pyramid  xTj[b][T_j][128f]  for j=0..3
// ---------------------------------------------------------------------------
__global__ __launch_bounds__(256) void prep_x(
    const float* __restrict__ x,
    ushort* __restrict__ xT0, ushort* __restrict__ xT1,
    ushort* __restrict__ xT2, ushort* __restrict__ xT3) {
  __shared__ float lt[128 * 65];
  const int b  = blockIdx.y;
  const int t0 = blockIdx.x * 64;
  const int tid = threadIdx.x;
  const int wv = tid >> 6, lane = tid & 63;
#pragma unroll
  for (int rep = 0; rep < 32; ++rep) {
    int f = rep * 4 + wv;
    lt[f * 65 + lane] = x[((size_t)b * 128 + f) * T_FULL + t0 + lane];
  }
  __syncthreads();
  ushort* dst[4] = {xT0, xT1, xT2, xT3};
  const int Ts[4] = {16384, 8192, 4096, 2048};
  for (int lvl = 0; lvl < 4; ++lvl) {
    int nt = 64 >> lvl, w = 1 << lvl;
    float inv = 1.f / (float)w;
    int tasks = nt * 16;
    for (int i = tid; i < tasks; i += 256) {
      int tl = i >> 4, fc = i & 15;
      __align__(16) ushort vs[8];
#pragma unroll
      for (int e = 0; e < 8; ++e) {
        float a = 0.f;
        for (int m = 0; m < w; ++m) a += lt[(fc * 8 + e) * 65 + tl * w + m];
        vs[e] = f2bf(a * inv);
      }
      ushort* pdst = dst[lvl] + ((size_t)b * Ts[lvl] + (t0 >> lvl) + tl) * 128 + fc * 8;
      *(uint4*)pdst = *(const uint4*)vs;
    }
  }
}

// ---------------------------------------------------------------------------
// conv_mfma: one octave. Block = 256 thr = 4 waves; tile = 16 f_out x 256 t.
// MFMA 16x16x32_bf16: M=ch16 (A=weights), N=pos16 (B=x), K=(4 dt x 8 df).
// Two output-f planes (fp, fp+4) fused per inner loop: each B ds_read_b128
// feeds 4 MFMAs.
// ---------------------------------------------------------------------------
template<int WP, int OCT>
__global__ __launch_bounds__(256) void conv_mfma(
    const ushort* __restrict__ xT, const ushort* __restrict__ wq,
    float* __restrict__ out, int Tj) {
  __shared__ ushort xt[388 * 56];
  const int tid = threadIdx.x;
  const int t0 = blockIdx.x * 256;
  const int f0 = blockIdx.y * 16;
  const int b  = blockIdx.z;

  // ---- stage transposed x tile: rows tloc 0..387 (t = t0-64+row), cols f0-16+[0,48) ----
  for (int i = tid; i < 388 * 6; i += 256) {
    int row = i / 6, fc = i % 6;
    int t = t0 - 64 + row;
    int f = f0 - 16 + fc * 8;             // chunk fully in or fully out of range
    uint4 v = make_uint4(0u, 0u, 0u, 0u);
    if (t >= 0 && t < Tj && f >= 0 && f < 128)
      v = *(const uint4*)(xT + ((size_t)b * Tj + t) * 128 + f);
    *(uint4*)&xt[row * 56 + fc * 8] = v;
  }
  __syncthreads();

  const int wave = tid >> 6, lane = tid & 63;
  const int p = lane & 15;                 // A-row = channel sel, B-col = position
  const int g = lane >> 4;                 // k-group (dt sub-index)

  const float invw = 1.f / (float)WP;

  for (int pair = 0; pair < 4; ++pair) {
    const int fpA = pair, fpB = pair + 4;
    const ushort* wA = wq + ((((size_t)OCT * 8 + fpA) * 16 + p) * 132 + g) * 40;
    const ushort* wB = wq + ((((size_t)OCT * 8 + fpB) * 16 + p) * 132 + g) * 40;
    int rbase = (p + g) * 56 + wave * 3584;   // ushort element offset in xt

    f32x4 accA[2][4], accB[2][4];
#pragma unroll
    for (int a = 0; a < 2; ++a)
#pragma unroll
      for (int r = 0; r < 4; ++r) {
        f32x4 z = {0.f, 0.f, 0.f, 0.f};
        accA[a][r] = z; accB[a][r] = z;
      }

    for (int c = 0; c < 33; ++c) {
      short8 ApA, AcA, ApB, AcB;
#pragma unroll
      for (int s = 0; s <= 5; ++s) {
        if (s < 5) {
          AcA = load_a16(wA + 8 * s);
          AcB = load_a16(wB + 8 * s);
        }
#pragma unroll
        for (int fr = 0; fr < 4; ++fr) {
          short8 bv = *(const short8*)&xt[rbase + fr * 896 + s * 8];
          if (s < 5) {
            accA[0][fr] = __builtin_amdgcn_mfma_f32_16x16x32_bf16(AcA, bv, accA[0][fr], 0, 0, 0);
            accB[0][fr] = __builtin_amdgcn_mfma_f32_16x16x32_bf16(AcB, bv, accB[0][fr], 0, 0, 0);
          }
          if (s > 0) {
            accA[1][fr] = __builtin_amdgcn_mfma_f32_16x16x32_bf16(ApA, bv, accA[1][fr], 0, 0, 0);
            accB[1][fr] = __builtin_amdgcn_mfma_f32_16x16x32_bf16(ApB, bv, accB[1][fr], 0, 0, 0);
          }
        }
        ApA = AcA; ApB = AcB;
      }
      wA += 160;                 // next c: dt += 4 -> 4*40 ushorts
      wB += 160;
      rbase += 224;              // next c: row += 4 -> 4*56 ushorts
    }

    // ---- epilogue: modulus (lane^32 pairs re/im) + avg-pool via butterfly ----
    auto epilogue = [&](f32x4 (&acc)[2][4], int fp) {
#pragma unroll
      for (int f2 = 0; f2 < 2; ++f2) {
        const int fo = f0 + fp + 8 * f2;
#pragma unroll
        for (int fr = 0; fr < 4; ++fr) {
          const int tbase = t0 + 16 * (4 * wave + fr);
#pragma unroll
          for (int r = 0; r < 4; ++r) {
            float a = acc[f2][fr][r];
            float o = __shfl_xor(a, 32);
            float m = sqrtf(a * a + o * o);
#pragma unroll
            for (int mask = WP / 2; mask >= 1; mask >>= 1)
              m += __shfl_xor(m, mask);
            if (((p & (WP - 1)) == 0) && g < 2) {
              int ch = 4 * g + r;
              int tcol = (tbase + p) / WP;
              out[(((size_t)b * 32 + OCT * 8 + ch) * 128 + fo) * 1024 + tcol] = m * invw;
            }
          }
        }
      }
    };
    epilogue(accA, fpA);
    epilogue(accB, fpB);
  }
}

// ---------------------------------------------------------------------------
extern "C" void kernel_launch(void* const* d_in, const int* in_sizes, int n_in,
                              void* d_out, int out_size, void* d_ws, size_t ws_size,
                              hipStream_t stream) {
  const float* x  = (const float*)d_in[0];
  const float* wr = (const float*)d_in[1];
  const float* wi = (const float*)d_in[2];
  float* out = (float*)d_out;

  ushort* xT0 = (ushort*)d_ws;                       // 4*16384*128
  ushort* xT1 = xT0 + (size_t)4 * 16384 * 128;       // 4*8192*128
  ushort* xT2 = xT1 + (size_t)4 * 8192 * 128;        // 4*4096*128
  ushort* xT3 = xT2 + (size_t)4 * 4096 * 128;        // 4*2048*128
  ushort* wq  = xT3 + (size_t)4 * 2048 * 128;        // 2703360

  prep_w<<<2703360 / 256, 256, 0, stream>>>(wr, wi, wq);
  prep_x<<<dim3(T_FULL / 64, B_), 256, 0, stream>>>(x, xT0, xT1, xT2, xT3);

  conv_mfma<16, 0><<<dim3(64, 8, 4), 256, 0, stream>>>(xT0, wq, out, 16384);
  conv_mfma< 8, 1><<<dim3(32, 8, 4), 256, 0, stream>>>(xT1, wq, out, 8192);
  conv_mfma< 4, 2><<<dim3(16, 8, 4), 256, 0, stream>>>(xT2, wq, out, 4096);
  conv_mfma< 2, 3><<<dim3( 8, 8, 4), 256, 0, stream>>>(xT3, wq, out, 2048);
}

// Round 4
// 1902.460 us; speedup vs baseline: 9.1970x; 1.0902x over previous
//
#include <hip/hip_runtime.h>
#include <math.h>

#define B_      4
#define F_BINS  128
#define T_FULL  16384
#define NW      8
#define KF      33
#define KT      129

typedef __attribute__((ext_vector_type(8))) short short8;
typedef __attribute__((ext_vector_type(4))) float f32x4;
typedef uint uint4a16 __attribute__((ext_vector_type(4), aligned(16)));

union ABFrag { uint4a16 u; short8 v; };

__device__ __forceinline__ ushort f2bf(float v) {
  unsigned u = __float_as_uint(v);
  unsigned r = (u + 0x7FFFu + ((u >> 16) & 1u)) >> 16;
  return (ushort)r;
}

__device__ __forceinline__ short8 load_a16(const ushort* p) {
  ABFrag f; f.u = *(const uint4a16*)p; return f.v;
}

// ---------------------------------------------------------------------------
// prep_w: fp-shifted, zero-padded bf16 weights
//   wq[oct 4][fp 4][ch 16][dt 132][d2i 48] = wav[ch][df = d2i - 8 - fp][dt]
//   (zero outside df in [0,33), dt in [0,129))
//   fp+4 / fp+8 / fp+12 planes are derived in-register from this layout.
// ---------------------------------------------------------------------------
__global__ __launch_bounds__(256) void prep_w(
    const float* __restrict__ wr, const float* __restrict__ wi,
    ushort* __restrict__ wq) {
  int idx = blockIdx.x * 256 + threadIdx.x;      // 4*4*16*132*48 = 1622016
  int d2i = idx % 48;
  int dt  = (idx / 48) % 132;
  int ch  = (idx / (48 * 132)) % 16;
  int fp  = (idx / (48 * 132 * 16)) % 4;
  int oct = idx / (48 * 132 * 16 * 4);
  int df  = d2i - 8 - fp;
  float v = 0.f;
  if (df >= 0 && df < KF && dt < KT) {
    const float* src = (ch < 8) ? wr : wi;
    v = src[(((size_t)oct * 8 + (ch & 7)) * KF + df) * KT + dt];
  }
  wq[idx] = f2bf(v);
}

// ---------------------------------------------------------------------------
// prep_x: bf16 transposed pyramid  xTj[b][T_j][128f]  for j=0..3
// ---------------------------------------------------------------------------
__global__ __launch_bounds__(256) void prep_x(
    const float* __restrict__ x,
    ushort* __restrict__ xT0, ushort* __restrict__ xT1,
    ushort* __restrict__ xT2, ushort* __restrict__ xT3) {
  __shared__ float lt[128 * 65];
  const int b  = blockIdx.y;
  const int t0 = blockIdx.x * 64;
  const int tid = threadIdx.x;
  const int wv = tid >> 6, lane = tid & 63;
#pragma unroll
  for (int rep = 0; rep < 32; ++rep) {
    int f = rep * 4 + wv;
    lt[f * 65 + lane] = x[((size_t)b * 128 + f) * T_FULL + t0 + lane];
  }
  __syncthreads();
  ushort* dst[4] = {xT0, xT1, xT2, xT3};
  const int Ts[4] = {16384, 8192, 4096, 2048};
  for (int lvl = 0; lvl < 4; ++lvl) {
    int nt = 64 >> lvl, w = 1 << lvl;
    float inv = 1.f / (float)w;
    int tasks = nt * 16;
    for (int i = tid; i < tasks; i += 256) {
      int tl = i >> 4, fc = i & 15;
      __align__(16) ushort vs[8];
#pragma unroll
      for (int e = 0; e < 8; ++e) {
        float a = 0.f;
        for (int m = 0; m < w; ++m) a += lt[(fc * 8 + e) * 65 + tl * w + m];
        vs[e] = f2bf(a * inv);
      }
      ushort* pdst = dst[lvl] + ((size_t)b * Ts[lvl] + (t0 >> lvl) + tl) * 128 + fc * 8;
      *(uint4*)pdst = *(const uint4*)vs;
    }
  }
}

// ---------------------------------------------------------------------------
// conv_mfma: one octave. Block = 256 thr = 4 waves; tile = 16 f_out x 256 t.
// MFMA 16x16x32_bf16: M=ch16 (A=weights), N=pos16 (B=x), K=(4 dt x 8 df).
// Per fp-iter computes 4 output-f planes {fp, fp+4, fp+8, fp+12}:
//   aA0: F[s+1]       -> fo = f0+fp
//   aB0: G[s]         -> fo = f0+fp+4    (G = d2-shift-by-4 register concat)
//   aA1: F[s]         -> fo = f0+fp+8    (window-shift trick)
//   aB1: G[s-1]       -> fo = f0+fp+12
// A-loads are double-buffered across c (6 x 16B per c, one base pointer).
// ---------------------------------------------------------------------------
template<int WP, int OCT>
__global__ __launch_bounds__(256, 3) void conv_mfma(
    const ushort* __restrict__ xT, const ushort* __restrict__ wq,
    float* __restrict__ out, int Tj) {
  __shared__ ushort xt[388 * 56];
  const int tid = threadIdx.x;
  const int t0 = blockIdx.x * 256;
  const int f0 = blockIdx.y * 16;
  const int b  = blockIdx.z;

  // ---- stage transposed x tile: rows 0..387 (t = t0-64+row), cols f0-16+[0,48) ----
  for (int i = tid; i < 388 * 6; i += 256) {
    int row = i / 6, fc = i % 6;
    int t = t0 - 64 + row;
    int f = f0 - 16 + fc * 8;             // chunk fully in or fully out of range
    uint4 v = make_uint4(0u, 0u, 0u, 0u);
    if (t >= 0 && t < Tj && f >= 0 && f < 128)
      v = *(const uint4*)(xT + ((size_t)b * Tj + t) * 128 + f);
    *(uint4*)&xt[row * 56 + fc * 8] = v;
  }
  __syncthreads();

  const int wave = tid >> 6, lane = tid & 63;
  const int p = lane & 15;                 // A-row = channel sel, B-col = position
  const int g = lane >> 4;                 // k-group (dt sub-index)

  const float invw = 1.f / (float)WP;

  for (int fp = 0; fp < 4; ++fp) {
    const ushort* wp = wq + ((((size_t)OCT * 4 + fp) * 16 + p) * 132 + g) * 48;
    int rb = (p + g) * 56 + wave * 3584;   // ushort element offset in xt

    f32x4 aA0[4], aA1[4], aB0[4], aB1[4];
#pragma unroll
    for (int r = 0; r < 4; ++r) {
      f32x4 z = {0.f, 0.f, 0.f, 0.f};
      aA0[r] = z; aA1[r] = z; aB0[r] = z; aB1[r] = z;
    }

    short8 Fa[6], Fb[6];

    auto load6 = [](short8 (&F)[6], const ushort* ptr) {
#pragma unroll
      for (int u = 0; u < 6; ++u) F[u] = load_a16(ptr + 8 * u);
    };

    auto body = [&](short8 (&F)[6], int rbase) {
      short8 G[5];
#pragma unroll
      for (int u = 0; u < 5; ++u)
        G[u] = __builtin_shufflevector(F[u], F[u + 1], 4, 5, 6, 7, 8, 9, 10, 11);
#pragma unroll
      for (int s = 0; s <= 5; ++s) {
#pragma unroll
        for (int fr = 0; fr < 4; ++fr) {
          short8 bv = *(const short8*)&xt[rbase + fr * 896 + s * 8];
          if (s < 5) {
            aA0[fr] = __builtin_amdgcn_mfma_f32_16x16x32_bf16(F[s + 1], bv, aA0[fr], 0, 0, 0);
            aB0[fr] = __builtin_amdgcn_mfma_f32_16x16x32_bf16(G[s],     bv, aB0[fr], 0, 0, 0);
          }
          if (s > 0) {
            aA1[fr] = __builtin_amdgcn_mfma_f32_16x16x32_bf16(F[s],     bv, aA1[fr], 0, 0, 0);
            aB1[fr] = __builtin_amdgcn_mfma_f32_16x16x32_bf16(G[s - 1], bv, aB1[fr], 0, 0, 0);
          }
        }
      }
    };

    // software-pipelined c-loop: 33 iterations = 16 x 2 + 1
    load6(Fa, wp);
#pragma unroll 1
    for (int cc = 0; cc < 16; ++cc) {
      load6(Fb, wp + 192);          // c = 2cc+1
      body(Fa, rb);                 // c = 2cc
      load6(Fa, wp + 384);          // c = 2cc+2 (cc=15 -> c=32)
      body(Fb, rb + 224);           // c = 2cc+1
      wp += 384; rb += 448;
    }
    body(Fa, rb);                   // c = 32

    // ---- epilogue: modulus (lane^32 pairs re/im) + avg-pool via butterfly ----
    auto epi = [&](f32x4 (&acc)[4], int fo) {
#pragma unroll
      for (int fr = 0; fr < 4; ++fr) {
        const int tbase = t0 + 16 * (4 * wave + fr);
#pragma unroll
        for (int r = 0; r < 4; ++r) {
          float a = acc[fr][r];
          float o = __shfl_xor(a, 32);
          float m = sqrtf(a * a + o * o);
#pragma unroll
          for (int mask = WP / 2; mask >= 1; mask >>= 1)
            m += __shfl_xor(m, mask);
          if (((p & (WP - 1)) == 0) && g < 2) {
            int ch = 4 * g + r;
            int tcol = (tbase + p) / WP;
            out[(((size_t)b * 32 + OCT * 8 + ch) * 128 + fo) * 1024 + tcol] = m * invw;
          }
        }
      }
    };
    epi(aA0, f0 + fp);
    epi(aB0, f0 + fp + 4);
    epi(aA1, f0 + fp + 8);
    epi(aB1, f0 + fp + 12);
  }
}

// ---------------------------------------------------------------------------
extern "C" void kernel_launch(void* const* d_in, const int* in_sizes, int n_in,
                              void* d_out, int out_size, void* d_ws, size_t ws_size,
                              hipStream_t stream) {
  const float* x  = (const float*)d_in[0];
  const float* wr = (const float*)d_in[1];
  const float* wi = (const float*)d_in[2];
  float* out = (float*)d_out;

  ushort* xT0 = (ushort*)d_ws;                       // 4*16384*128
  ushort* xT1 = xT0 + (size_t)4 * 16384 * 128;       // 4*8192*128
  ushort* xT2 = xT1 + (size_t)4 * 8192 * 128;        // 4*4096*128
  ushort* xT3 = xT2 + (size_t)4 * 4096 * 128;        // 4*2048*128
  ushort* wq  = xT3 + (size_t)4 * 2048 * 128;        // 1622016

  prep_w<<<1622016 / 256, 256, 0, stream>>>(wr, wi, wq);
  prep_x<<<dim3(T_FULL / 64, B_), 256, 0, stream>>>(x, xT0, xT1, xT2, xT3);

  conv_mfma<16, 0><<<dim3(64, 8, 4), 256, 0, stream>>>(xT0, wq, out, 16384);
  conv_mfma< 8, 1><<<dim3(32, 8, 4), 256, 0, stream>>>(xT1, wq, out, 8192);
  conv_mfma< 4, 2><<<dim3(16, 8, 4), 256, 0, stream>>>(xT2, wq, out, 4096);
  conv_mfma< 2, 3><<<dim3( 8, 8, 4), 256, 0, stream>>>(xT3, wq, out, 2048);
}